// Round 9
// baseline (119.255 us; speedup 1.0000x reference)
//
#include <hip/hip_runtime.h>

// Viterbi trellis quantizer: S=1024 states, K=2 (4 predecessors), CHUNK=4,
// block_size=16 -> T=64 steps/chain, B=4096 chains (16x16 blocks of 1024^2).
//
// One 64-lane wave per chain (R3's proven-best launch shape).
// beta-formulation: beta_t[s] = M_{t-1}[s>>2] + (cb[s]·x_t + h[s]),
//   h = -||cb||^2/2, M_t[p] = max_j beta_t[p + 256j], M_{-1} = 0.
//
// R11: REGISTER-ONLY recursion. Evidence: R3..R10 all share a ~2200cyc/step
// wall vs ~250cyc of issue work; the invariant is the loop-carried LDS round
// trip (M write -> read-back). R10 tried to hide it (failed); remove it.
//
// Lane remap that makes a pure-shuffle exchange legal:
//   lane L owns states s = L + 64i + 256j  (i,j in 0..3)
//   -> production: groups p = L + 64i have ALL candidates p+256j owned by L;
//      M[L+64i] lives in register mprev[i].
//   -> consumption: state (i,j) needs M[(L>>2) + 16i + 64j]
//      = register j of lane (L>>2)+16i: UNIFORM reg per fetch, uniform addr
//      per i -> exactly 16 ds_bpermute_b32 with t-invariant addresses.
// (With the old s=4L+c+256j map, 4 dest lanes need 4 different regs of one
// source lane -> no bpermute exchange exists; this remap is the fix.)
// Loop-carried path: max -> bpermute -> add -> max (~1 LDS-crossbar latency);
// the 64 M-independent FMAs cover it. No Mst LDS, no lockstep assumption.
//
// Numerics: same fmaf chain per state, same "+m" placement, same j-ascending
// first-max, final argmax visits states in ascending s (j-major, i-minor)
// -> decisions bit-identical to R3. J packing: lane L stores groups L+64i
// as 2-bit fields: byte Jb[t*64 + (p&63)], field 2*(p>>6).
// Launch config: R3's proven best (128thr, 2048 blocks, waves_per_eu(4,4)).
// Tripwire: WRITE_SIZE > 5120 KB = spill.

#define COLS      1024
#define T_STEPS   64
#define REC_SIZE  (1024 * 1024)

__global__ __launch_bounds__(128)
__attribute__((amdgpu_waves_per_eu(4, 4)))
void viterbi_q(
    const float* __restrict__ arr,
    const float* __restrict__ cbook,
    float* __restrict__ out)
{
    const int tid   = threadIdx.x;
    const int wid   = tid >> 6;      // chain slot in block (0..1)
    const int lane  = tid & 63;
    const int chain = (blockIdx.x << 1) | wid;   // 0..4095
    const int rb    = chain >> 6;    // block-row
    const int cb    = chain & 63;    // block-col

    __shared__ __align__(16) float tile[2][256];   // x chunks for the chain
    __shared__ unsigned char Jb[2][63 * 64];       // packed backpointers
    __shared__ int st_lds[2][64];                  // traced-back states

    // ---- stage this chain's 16x16 tile into LDS (tile[e], e = r*16 + c) ----
    {
        const int r  = lane >> 2;
        const int c4 = (lane & 3) << 2;
        float4 v = *(const float4*)(arr + (rb * 16 + r) * COLS + cb * 16 + c4);
        *(float4*)&tile[wid][lane << 2] = v;
    }

    // ---- codebook rows for this lane's 16 states: s = lane + 64i + 256j ----
    float4 a[16];   // raw codebook row, index (i<<2)|j
    float  h[16];   // -||row||^2 / 2
    #pragma unroll
    for (int i = 0; i < 4; ++i) {
        #pragma unroll
        for (int j = 0; j < 4; ++j) {
            const int row = lane + (i << 6) + (j << 8);
            float4 v = *(const float4*)(cbook + row * 4);
            a[(i << 2) | j] = v;
            h[(i << 2) | j] = -0.5f * (v.x * v.x + v.y * v.y +
                                       v.z * v.z + v.w * v.w);
        }
    }

    // t-invariant bpermute byte-addresses: source lane for i = (lane>>2)+16i
    int ba[4];
    #pragma unroll
    for (int i = 0; i < 4; ++i)
        ba[i] = ((lane >> 2) + (i << 4)) << 2;

    const float* __restrict__ tilep = &tile[wid][0];
    unsigned char* __restrict__ Jp  = &Jb[wid][0];

    float mprev[4] = {0.f, 0.f, 0.f, 0.f};   // M_{t-1}[lane + 64i]; M_{-1}=0

    // mm[(i<<2)|j] = M_{t-1}[(lane>>2) + 16i + 64j] via 16 bpermutes
#define FETCH_MM(MM)                                                          \
    _Pragma("unroll")                                                         \
    for (int i = 0; i < 4; ++i) {                                             \
        _Pragma("unroll")                                                     \
        for (int j = 0; j < 4; ++j)                                           \
            (MM)[(i << 2) | j] = __int_as_float(                              \
                __builtin_amdgcn_ds_bpermute(ba[i],                           \
                                             __float_as_int(mprev[j])));      \
    }

    // ---- forward recursion, t = 0..62: register-only M exchange ----
    #pragma unroll 1
    for (int t = 0; t < T_STEPS - 1; ++t) {
        float mm[16];
        FETCH_MM(mm)                         // depends only on last iter's max
        const float4 xt = *(const float4*)&tilep[t << 2];   // broadcast read

        unsigned bp = 0;
        #pragma unroll
        for (int i = 0; i < 4; ++i) {        // group p = lane + 64i
            float cand[4];
            #pragma unroll
            for (int j = 0; j < 4; ++j) {    // predecessor p + 256j
                const float4 av = a[(i << 2) | j];
                float acc = fmaf(av.x, xt.x, h[(i << 2) | j]);
                acc = fmaf(av.y, xt.y, acc);
                acc = fmaf(av.z, xt.z, acc);
                acc = fmaf(av.w, xt.w, acc);
                cand[j] = acc + mm[(i << 2) | j];
            }
            const float v = fmaxf(fmaxf(fmaxf(cand[0], cand[1]), cand[2]),
                                  cand[3]);
            // first-max index == reference's first-min over alpha candidates
            const int j = (cand[0] == v) ? 0
                        : (cand[1] == v) ? 1
                        : (cand[2] == v) ? 2 : 3;
            mprev[i] = v;
            bp |= (unsigned)j << (2 * i);
        }
        Jp[t * 64 + lane] = (unsigned char)bp;
    }

    // ---- final step t = 63: full argmax over beta_63[0..1023] ----
    int bests;
    {
        float mm[16];
        FETCH_MM(mm)
        const float4 xt = *(const float4*)&tilep[63 << 2];

        float bv = -3.4e38f;
        int   bs = 0;
        #pragma unroll
        for (int j = 0; j < 4; ++j) {        // ascending s: j major, i minor
            #pragma unroll
            for (int i = 0; i < 4; ++i) {
                const float4 av = a[(i << 2) | j];
                float acc = fmaf(av.x, xt.x, h[(i << 2) | j]);
                acc = fmaf(av.y, xt.y, acc);
                acc = fmaf(av.z, xt.z, acc);
                acc = fmaf(av.w, xt.w, acc);
                acc += mm[(i << 2) | j];
                if (acc > bv) { bv = acc; bs = lane + (i << 6) + (j << 8); }
            }
        }
        // lexicographic (value desc, state asc) butterfly across the wave
        #pragma unroll
        for (int off = 32; off > 0; off >>= 1) {
            const float ov = __shfl_xor(bv, off, 64);
            const int   os = __shfl_xor(bs, off, 64);
            if (ov > bv || (ov == bv && os < bs)) { bv = ov; bs = os; }
        }
        bests = bs;
    }
#undef FETCH_MM

    // ---- traceback (serial, lane 0 of each wave) ----
    if (lane == 0) {
        int s = bests;
        st_lds[wid][T_STEPS - 1] = s;
        for (int i = T_STEPS - 2; i >= 0; --i) {
            const int p = s >> 2;                       // group of s
            const unsigned byte = Jp[i * 64 + (p & 63)];
            const int j = (byte >> (2 * (p >> 6))) & 3;
            s = p + (j << 8);                           // predecessor state
            st_lds[wid][i] = s;
        }
    }
    // NO barrier: st_lds[wid] is written by lane 0 of THIS wave and read by
    // the same wave below; wave-lockstep + in-order same-wave DS ordering.

    // ---- outputs: lane i handles step t = i ----
    const int st = st_lds[wid][lane];
    // states_out flat: REC_SIZE + chain*64 + t   (stored as float values)
    out[REC_SIZE + chain * 64 + lane] = (float)st;
    // rec: step t covers elements e = 4t..4t+3 -> row t>>2, cols 4*(t&3)..+3
    const float4 v = *(const float4*)(cbook + st * 4);
    const int r  = lane >> 2;
    const int c4 = (lane & 3) << 2;
    *(float4*)(out + (rb * 16 + r) * COLS + cb * 16 + c4) = v;
}

extern "C" void kernel_launch(void* const* d_in, const int* in_sizes, int n_in,
                              void* d_out, int out_size, void* d_ws, size_t ws_size,
                              hipStream_t stream)
{
    const float* arr   = (const float*)d_in[0];
    const float* cbook = (const float*)d_in[1];
    float* out = (float*)d_out;
    // 4096 chains, 2 chains (waves) per 128-thread block -> 2048 blocks
    viterbi_q<<<dim3(2048), dim3(128), 0, stream>>>(arr, cbook, out);
}